// Round 9
// baseline (131.727 us; speedup 1.0000x reference)
//
#include <hip/hip_runtime.h>

// f32 parts that must be bit-exact vs numpy (denom chain, clamps) forbid FMA
// contraction. The affine-coefficient algebra is done in f64 and rounded once.
#pragma clang fp contract(off)

#define B_ 32
#define H_ 512
#define W_ 384
#define V_ 6890
#define F_ 13776
#define PAD_ 64          // (H - W) / 2
#define WP_ 512          // W + 2*PAD

// Native clang vector types (HIP's int4/float4 are classes, rejected by
// __builtin_nontemporal_load/store).
typedef int   vint4   __attribute__((ext_vector_type(4)));
typedef float vfloat2 __attribute__((ext_vector_type(2)));

// RULES learned:
// r7: nontemporal is ONLY safe when one instruction's 64 lanes cover whole
//     64B lines (partial-line nt amplifies HBM traffic ~1.5x).
// r8: nt load in the byte-scatter kernel cost ~30us (A/B evidence, mechanism
//     unresolved) -> scatter uses plain cached loads.

// Per-(b,f) record: 32 bytes (2 records per 64B line).
// r0: [A'x, Bx, Cx, A'y]   corr_x = A'x + px*Bx + py*Cx
// r1: [By, Cy, flags, 0]   corr_y = A'y + px*By + py*Cy
// flags bit0 = vis2f, bit1 = sym_ok.

// ---------------------------------------------------------------------------
// Kernel 1: vf2[b][f] = any view-2 pixel sees face f. Plain cached int4
// reads (r8 rule), idempotent byte stores. XCD-chunk swizzled.
// ---------------------------------------------------------------------------
__global__ __launch_bounds__(256) void vf2_scatter_kernel(
    const vint4* __restrict__ vis_2_v4, unsigned char* __restrict__ vf2)
{
    unsigned bid = blockIdx.x;
    unsigned cpx = gridDim.x >> 3;                 // gridDim divisible by 8
    unsigned swz = (bid & 7u) * cpx + (bid >> 3);
    int idx = (int)(swz * blockDim.x + threadIdx.x);
    const int total4 = B_ * H_ * W_ / 4;
    if (idx >= total4) return;
    vint4 v = vis_2_v4[idx];
    int b = idx / (H_ * W_ / 4);                   // groups never cross b
    unsigned char* t = vf2 + (size_t)b * F_;
    if (v.x >= 0) t[v.x] = 1;
    if (v.y >= 0) t[v.y] = 1;
    if (v.z >= 0) t[v.z] = 1;
    if (v.w >= 0) t[v.w] = 1;
}

// ---------------------------------------------------------------------------
// Kernel 2: build 32B affine records. denom/flags bit-exact in f32 (ref op
// order); coefficient algebra in f64, rounded once to f32.
// ---------------------------------------------------------------------------
__global__ __launch_bounds__(256) void face_precompute_kernel(
    const float* __restrict__ verts_1,
    const float* __restrict__ verts_2,
    const int*   __restrict__ face,
    const int*   __restrict__ symtab,
    const unsigned char* __restrict__ vf2,
    float4* __restrict__ recs)            // B*F*2 float4s
{
#pragma clang fp contract(off)
    int idx = blockIdx.x * blockDim.x + threadIdx.x;
    const int total = B_ * F_;
    if (idx >= total) return;
    int f = idx % F_;
    int b = idx / F_;

    int i0 = face[f * 3 + 0];
    int i1 = face[f * 3 + 1];
    int i2 = face[f * 3 + 2];

    const float* v1b = verts_1 + (size_t)b * (V_ * 3);
    float ax = v1b[i0 * 3 + 0], ay = v1b[i0 * 3 + 1];
    float bx = v1b[i1 * 3 + 0], by = v1b[i1 * 3 + 1];
    float cx = v1b[i2 * 3 + 0], cy = v1b[i2 * 3 + 1];

    // f32, exact reference op order (these feed the denom clamp decision).
    float e0x = bx - ax, e0y = by - ay;
    float e1x = cx - ax, e1y = cy - ay;
    float d00 = (e0x * e0x) + (e0y * e0y);
    float d01 = (e0x * e1x) + (e0y * e1y);
    float d11 = (e1x * e1x) + (e1y * e1y);
    float denom = (d00 * d11) - (d01 * d01);
    if (fabsf(denom) < 1e-12f) denom = 1.0f;

    bool vis2f = vf2[idx] != 0;
    int s0 = symtab[i0], s1 = symtab[i1], s2 = symtab[i2];
    bool sym_ok = (s0 >= 0) && (s1 >= 0) && (s2 >= 0);

    int t0 = (!vis2f && sym_ok) ? s0 : i0;
    int t1 = (!vis2f && sym_ok) ? s1 : i1;
    int t2 = (!vis2f && sym_ok) ? s2 : i2;

    const float* v2b = verts_2 + (size_t)b * (V_ * 3);
    float q0x = v2b[t0 * 3 + 0], q0y = v2b[t0 * 3 + 1];
    float q1x = v2b[t1 * 3 + 0], q1y = v2b[t1 * 3 + 1];
    float q2x = v2b[t2 * 3 + 0], q2y = v2b[t2 * 3 + 1];

    // f64 affine algebra: corr_x = A'x + px*Bx + py*Cx  (e2 = p - a folded)
    double dd00 = (double)d00, dd01 = (double)d01, dd11 = (double)d11;
    double dden = (double)denom;
    double De0x = (double)e0x, De0y = (double)e0y;
    double De1x = (double)e1x, De1y = (double)e1y;

    double Ux = (dd11 * De0x - dd01 * De1x) / dden;
    double Uy = (dd11 * De0y - dd01 * De1y) / dden;
    double Vx = (dd00 * De1x - dd01 * De0x) / dden;
    double Vy = (dd00 * De1y - dd01 * De0y) / dden;

    double dq1x = (double)q1x - (double)q0x;
    double dq2x = (double)q2x - (double)q0x;
    double dq1y = (double)q1y - (double)q0y;
    double dq2y = (double)q2y - (double)q0y;

    double Bx = Ux * dq1x + Vx * dq2x;
    double Cx = Uy * dq1x + Vy * dq2x;
    double By = Ux * dq1y + Vx * dq2y;
    double Cy = Uy * dq1y + Vy * dq2y;

    double Apx = (double)q0x - (double)ax * Bx - (double)ay * Cx;
    double Apy = (double)q0y - (double)ax * By - (double)ay * Cy;

    unsigned flags = (vis2f ? 1u : 0u) | (sym_ok ? 2u : 0u);

    float4* r = recs + (size_t)idx * 2;
    r[0] = make_float4((float)Apx, (float)Bx, (float)Cx, (float)Apy);
    r[1] = make_float4((float)By, (float)Cy, __uint_as_float(flags), 0.0f);
}

// ---------------------------------------------------------------------------
// Kernel 3: main. One wave = TWO consecutive 512-px padded rows (same b:
// H even, row pairs aligned). Lane l owns pixel xp = k*64+l of each row.
// Pipeline: issue all 24 streaming nt loads, then 24 record gathers (row-B
// gathers overlap row-A's in flight), then compute+store both rows.
// All streaming accesses lane-contiguous => full 64B lines (r7 rule).
// ---------------------------------------------------------------------------
__global__ __launch_bounds__(256) void flow_main_kernel(
    const int*   __restrict__ vis_1,
    const float* __restrict__ vis_sym_mask_1,
    const float4* __restrict__ recs,
    float* __restrict__ out_grid,    // B*H*WP*2 floats
    float* __restrict__ corr_mask)   // B*H*WP floats
{
#pragma clang fp contract(off)
    unsigned bid = blockIdx.x;
    unsigned cpx = gridDim.x >> 3;                 // 2048/8 = 256
    unsigned swz = (bid & 7u) * cpx + (bid >> 3);
    int gtid = (int)(swz * blockDim.x + threadIdx.x);
    int wid  = gtid >> 6;                          // wave id in [0, 8192)
    int lane = (int)(threadIdx.x & 63u);
    int rA   = wid * 2;                            // rows rA, rA+1 (same b)
    int yA   = rA & (H_ - 1);
    int b    = rA >> 9;                            // rA / H_

    int   vis[2][6];
    float msk[2][6];
    float4 R0[2][6], R1[2][6];
    bool  bgs[2][6];

    // 24 streaming nt loads (independent, all issued up front).
    #pragma unroll
    for (int rr = 0; rr < 2; ++rr) {
        const int*   vr = vis_1          + (size_t)(rA + rr) * W_;
        const float* mr = vis_sym_mask_1 + (size_t)(rA + rr) * W_;
        #pragma unroll
        for (int j = 0; j < 6; ++j) {
            vis[rr][j] = __builtin_nontemporal_load(vr + j * 64 + lane);
            msk[rr][j] = __builtin_nontemporal_load(mr + j * 64 + lane);
        }
    }

    // 24 record gathers (cached; records are the reuse data, L2-resident).
    const float4* recb = recs + (size_t)b * F_ * 2;
    #pragma unroll
    for (int rr = 0; rr < 2; ++rr) {
        #pragma unroll
        for (int j = 0; j < 6; ++j) {
            bgs[rr][j] = vis[rr][j] < 0;
            int fc = bgs[rr][j] ? 0 : vis[rr][j];
            const float4* r = recb + (size_t)fc * 2;
            R0[rr][j] = r[0];
            R1[rr][j] = r[1];
        }
    }

    // Pad columns (k=0 and k=7) for both rows: full-line nt constant stores.
    #pragma unroll
    for (int rr = 0; rr < 2; ++rr) {
        vfloat2* ogrow = (vfloat2*)out_grid + (size_t)(rA + rr) * WP_;
        float*   cmrow = corr_mask          + (size_t)(rA + rr) * WP_;
        vfloat2 pv = { -1.0f, -1.0f };
        __builtin_nontemporal_store(pv, ogrow + lane);
        __builtin_nontemporal_store(pv, ogrow + 448 + lane);
        __builtin_nontemporal_store(2.0f, cmrow + lane);
        __builtin_nontemporal_store(2.0f, cmrow + 448 + lane);
    }

    // Compute + store both rows.
    #pragma unroll
    for (int rr = 0; rr < 2; ++rr) {
        int   y  = yA + rr;
        float py = (float)y;
        vfloat2* ogrow = (vfloat2*)out_grid + (size_t)(rA + rr) * WP_;
        float*   cmrow = corr_mask          + (size_t)(rA + rr) * WP_;

        #pragma unroll
        for (int j = 0; j < 6; ++j) {
            float Apx = R0[rr][j].x, Bx = R0[rr][j].y;
            float Cx  = R0[rr][j].z, Apy = R0[rr][j].w;
            float By  = R1[rr][j].x, Cy = R1[rr][j].y;
            unsigned flags = __float_as_uint(R1[rr][j].z);
            bool vis2f  = (flags & 1u) != 0;
            bool sym_ok = (flags & 2u) != 0;

            int   x  = j * 64 + lane;
            int   xp = x + PAD_;
            float px = (float)x;

            float corr_x = ((px * Bx) + (py * Cx)) + Apx;
            float corr_y = ((px * By) + (py * Cy)) + Apy;

            bool bg = bgs[rr][j];
            bool use_sym  = (!vis2f) && sym_ok && (msk[rr][j] > 0.0f) && (!bg);
            bool has_corr = (!bg) && (vis2f || use_sym);
            if (!has_corr) { corr_x = 0.0f; corr_y = 0.0f; }

            corr_x = corr_x + (float)PAD_;

            // Replicate flow = corr - base; grid = base + flow (roundings!).
            float base_x = (float)xp, base_y = py;
            float fx = corr_x - base_x;
            float fy = corr_y - base_y;
            float gxv = base_x + fx;
            float gyv = base_y + fy;

            float gx = ((2.0f * gxv) / (float)(WP_ - 1)) - 1.0f;
            float gy = ((2.0f * gyv) / (float)(H_  - 1)) - 1.0f;
            float cm = bg ? 2.0f : (has_corr ? 0.0f : 1.0f);

            vfloat2 ov = { gx, gy };
            __builtin_nontemporal_store(ov, ogrow + xp);   // 512B/instr
            __builtin_nontemporal_store(cm, cmrow + xp);   // 256B/instr
        }
    }
}

extern "C" void kernel_launch(void* const* d_in, const int* in_sizes, int n_in,
                              void* d_out, int out_size, void* d_ws, size_t ws_size,
                              hipStream_t stream)
{
    const float* verts_1 = (const float*)d_in[0];
    const int*   vis_1   = (const int*)d_in[1];
    const float* verts_2 = (const float*)d_in[2];
    const int*   vis_2   = (const int*)d_in[3];
    const int*   face    = (const int*)d_in[4];
    const float* vis_sym = (const float*)d_in[5];
    const int*   symtab  = (const int*)d_in[6];

    float* out_grid  = (float*)d_out;                              // B*H*WP*2
    float* corr_mask = (float*)d_out + (size_t)B_ * H_ * WP_ * 2;  // B*H*WP

    // Workspace: [vf2: B*F bytes][align 64][recs: B*F*32 bytes]
    unsigned char* vf2 = (unsigned char*)d_ws;
    size_t rec_off = ((size_t)B_ * F_ + 63) & ~(size_t)63;
    float4* recs = (float4*)((unsigned char*)d_ws + rec_off);

    (void)hipMemsetAsync(vf2, 0, (size_t)B_ * F_, stream);

    {
        const int total4 = B_ * H_ * W_ / 4;          // 1572864
        const int block  = 256;
        const int grid   = total4 / block;            // 6144, %8 == 0
        vf2_scatter_kernel<<<grid, block, 0, stream>>>(
            (const vint4*)vis_2, vf2);
    }
    {
        const int total = B_ * F_;                    // 440832
        const int block = 256;
        face_precompute_kernel<<<(total + block - 1) / block, block, 0, stream>>>(
            verts_1, verts_2, face, symtab, vf2, recs);
    }
    {
        const int waves = B_ * H_ / 2;                // 8192 (2 rows/wave)
        const int block = 256;                        // 4 waves/block
        const int grid  = waves / 4;                  // 2048, %8 == 0
        flow_main_kernel<<<grid, block, 0, stream>>>(
            vis_1, vis_sym, recs, out_grid, corr_mask);
    }
}

// Round 10
// 95.385 us; speedup vs baseline: 1.3810x; 1.3810x over previous
//
#include <hip/hip_runtime.h>

// f32 parts that must be bit-exact vs numpy (denom chain, clamps) forbid FMA
// contraction. The affine-coefficient algebra is done in f64 and rounded once.
#pragma clang fp contract(off)

#define B_ 32
#define H_ 512
#define W_ 384
#define V_ 6890
#define F_ 13776
#define PAD_ 64          // (H - W) / 2
#define WP_ 512          // W + 2*PAD

typedef int   vint4   __attribute__((ext_vector_type(4)));
typedef float vfloat2 __attribute__((ext_vector_type(2)));

// RULES learned this session:
// r7: partial-line nontemporal amplifies HBM traffic ~1.5x (nt = no-allocate;
//     the other half of the line re-fetches/rewrites from HBM).
// r9: ANY nt in the main kernel costs ~30us OUTSIDE its own dispatch window
//     (others 23 -> 52 us, 3-for-3 A/B across r7/r8/r9; scatter-nt exonerated
//     by r9). => NO nontemporal anywhere. All accesses cached.

// Per-(b,f) record: 32 bytes (2 records per 64B line).
// r0: [A'x, Bx, Cx, A'y]   corr_x = A'x + px*Bx + py*Cx
// r1: [By, Cy, flags, 0]   corr_y = A'y + px*By + py*Cy
// flags bit0 = vis2f, bit1 = sym_ok.

// ---------------------------------------------------------------------------
// Kernel 1: vf2[b][f] = any view-2 pixel sees face f. Plain cached int4
// reads, idempotent byte stores. XCD-chunk swizzled.
// ---------------------------------------------------------------------------
__global__ __launch_bounds__(256) void vf2_scatter_kernel(
    const vint4* __restrict__ vis_2_v4, unsigned char* __restrict__ vf2)
{
    unsigned bid = blockIdx.x;
    unsigned cpx = gridDim.x >> 3;                 // gridDim divisible by 8
    unsigned swz = (bid & 7u) * cpx + (bid >> 3);
    int idx = (int)(swz * blockDim.x + threadIdx.x);
    const int total4 = B_ * H_ * W_ / 4;
    if (idx >= total4) return;
    vint4 v = vis_2_v4[idx];
    int b = idx / (H_ * W_ / 4);                   // groups never cross b
    unsigned char* t = vf2 + (size_t)b * F_;
    if (v.x >= 0) t[v.x] = 1;
    if (v.y >= 0) t[v.y] = 1;
    if (v.z >= 0) t[v.z] = 1;
    if (v.w >= 0) t[v.w] = 1;
}

// ---------------------------------------------------------------------------
// Kernel 2: build 32B affine records. denom/flags bit-exact in f32 (ref op
// order); coefficient algebra in f64, rounded once to f32.
// ---------------------------------------------------------------------------
__global__ __launch_bounds__(256) void face_precompute_kernel(
    const float* __restrict__ verts_1,
    const float* __restrict__ verts_2,
    const int*   __restrict__ face,
    const int*   __restrict__ symtab,
    const unsigned char* __restrict__ vf2,
    float4* __restrict__ recs)            // B*F*2 float4s
{
#pragma clang fp contract(off)
    int idx = blockIdx.x * blockDim.x + threadIdx.x;
    const int total = B_ * F_;
    if (idx >= total) return;
    int f = idx % F_;
    int b = idx / F_;

    int i0 = face[f * 3 + 0];
    int i1 = face[f * 3 + 1];
    int i2 = face[f * 3 + 2];

    const float* v1b = verts_1 + (size_t)b * (V_ * 3);
    float ax = v1b[i0 * 3 + 0], ay = v1b[i0 * 3 + 1];
    float bx = v1b[i1 * 3 + 0], by = v1b[i1 * 3 + 1];
    float cx = v1b[i2 * 3 + 0], cy = v1b[i2 * 3 + 1];

    // f32, exact reference op order (these feed the denom clamp decision).
    float e0x = bx - ax, e0y = by - ay;
    float e1x = cx - ax, e1y = cy - ay;
    float d00 = (e0x * e0x) + (e0y * e0y);
    float d01 = (e0x * e1x) + (e0y * e1y);
    float d11 = (e1x * e1x) + (e1y * e1y);
    float denom = (d00 * d11) - (d01 * d01);
    if (fabsf(denom) < 1e-12f) denom = 1.0f;

    bool vis2f = vf2[idx] != 0;
    int s0 = symtab[i0], s1 = symtab[i1], s2 = symtab[i2];
    bool sym_ok = (s0 >= 0) && (s1 >= 0) && (s2 >= 0);

    int t0 = (!vis2f && sym_ok) ? s0 : i0;
    int t1 = (!vis2f && sym_ok) ? s1 : i1;
    int t2 = (!vis2f && sym_ok) ? s2 : i2;

    const float* v2b = verts_2 + (size_t)b * (V_ * 3);
    float q0x = v2b[t0 * 3 + 0], q0y = v2b[t0 * 3 + 1];
    float q1x = v2b[t1 * 3 + 0], q1y = v2b[t1 * 3 + 1];
    float q2x = v2b[t2 * 3 + 0], q2y = v2b[t2 * 3 + 1];

    // f64 affine algebra: corr_x = A'x + px*Bx + py*Cx  (e2 = p - a folded)
    double dd00 = (double)d00, dd01 = (double)d01, dd11 = (double)d11;
    double dden = (double)denom;
    double De0x = (double)e0x, De0y = (double)e0y;
    double De1x = (double)e1x, De1y = (double)e1y;

    double Ux = (dd11 * De0x - dd01 * De1x) / dden;
    double Uy = (dd11 * De0y - dd01 * De1y) / dden;
    double Vx = (dd00 * De1x - dd01 * De0x) / dden;
    double Vy = (dd00 * De1y - dd01 * De0y) / dden;

    double dq1x = (double)q1x - (double)q0x;
    double dq2x = (double)q2x - (double)q0x;
    double dq1y = (double)q1y - (double)q0y;
    double dq2y = (double)q2y - (double)q0y;

    double Bx = Ux * dq1x + Vx * dq2x;
    double Cx = Uy * dq1x + Vy * dq2x;
    double By = Ux * dq1y + Vx * dq2y;
    double Cy = Uy * dq1y + Vy * dq2y;

    double Apx = (double)q0x - (double)ax * Bx - (double)ay * Cx;
    double Apy = (double)q0y - (double)ax * By - (double)ay * Cy;

    unsigned flags = (vis2f ? 1u : 0u) | (sym_ok ? 2u : 0u);

    float4* r = recs + (size_t)idx * 2;
    r[0] = make_float4((float)Apx, (float)Bx, (float)Cx, (float)Apy);
    r[1] = make_float4((float)By, (float)Cy, __uint_as_float(flags), 0.0f);
}

// ---------------------------------------------------------------------------
// Kernel 3: main. One wave = one 512-px padded row; group k (k=0..7) gives
// lane l pixel xp = k*64+l; groups 0 and 7 are pad. All streaming accesses
// lane-contiguous (full 64B lines), ALL CACHED (r9 rule). 12 record gathers
// in flight per thread; records L2-resident (~1.8 MB/XCD via swizzle).
// ---------------------------------------------------------------------------
__global__ __launch_bounds__(256) void flow_main_kernel(
    const int*   __restrict__ vis_1,
    const float* __restrict__ vis_sym_mask_1,
    const float4* __restrict__ recs,
    float* __restrict__ out_grid,    // B*H*WP*2 floats
    float* __restrict__ corr_mask)   // B*H*WP floats
{
#pragma clang fp contract(off)
    unsigned bid = blockIdx.x;
    unsigned cpx = gridDim.x >> 3;                 // 4096/8 = 512
    unsigned swz = (bid & 7u) * cpx + (bid >> 3);
    int gtid = (int)(swz * blockDim.x + threadIdx.x);
    int row  = gtid >> 6;                          // in [0, B*H)
    int lane = (int)(threadIdx.x & 63u);
    int y = row & (H_ - 1);
    int b = row >> 9;                              // row / H_

    const int*   visrow = vis_1          + (size_t)row * W_;
    const float* mskrow = vis_sym_mask_1 + (size_t)row * W_;
    vfloat2*     ogrow  = (vfloat2*)out_grid + (size_t)row * WP_;
    float*       cmrow  = corr_mask      + (size_t)row * WP_;

    // Pad groups k=0 and k=7: full-line constant stores.
    {
        vfloat2 pv = { -1.0f, -1.0f };
        ogrow[lane]       = pv;
        ogrow[448 + lane] = pv;
        cmrow[lane]       = 2.0f;
        cmrow[448 + lane] = 2.0f;
    }

    // Interior groups j=0..5: x = j*64+lane, xp = x+64.
    int   vis[6];
    float msk[6];
    #pragma unroll
    for (int j = 0; j < 6; ++j) {
        vis[j] = visrow[j * 64 + lane];
        msk[j] = mskrow[j * 64 + lane];
    }

    // Issue all 12 record loads (independent chains, L2-resident data).
    float4 R0[6], R1[6];
    bool   bgs[6];
    #pragma unroll
    for (int j = 0; j < 6; ++j) {
        bgs[j] = vis[j] < 0;
        int fc = bgs[j] ? 0 : vis[j];
        const float4* r = recs + ((size_t)b * F_ + fc) * 2;
        R0[j] = r[0];
        R1[j] = r[1];
    }

    #pragma unroll
    for (int j = 0; j < 6; ++j) {
        float Apx = R0[j].x, Bx = R0[j].y, Cx = R0[j].z, Apy = R0[j].w;
        float By  = R1[j].x, Cy = R1[j].y;
        unsigned flags = __float_as_uint(R1[j].z);
        bool vis2f  = (flags & 1u) != 0;
        bool sym_ok = (flags & 2u) != 0;

        int   x  = j * 64 + lane;
        int   xp = x + PAD_;
        float px = (float)x, py = (float)y;

        float corr_x = ((px * Bx) + (py * Cx)) + Apx;
        float corr_y = ((px * By) + (py * Cy)) + Apy;

        bool bg = bgs[j];
        bool use_sym  = (!vis2f) && sym_ok && (msk[j] > 0.0f) && (!bg);
        bool has_corr = (!bg) && (vis2f || use_sym);
        if (!has_corr) { corr_x = 0.0f; corr_y = 0.0f; }

        corr_x = corr_x + (float)PAD_;

        // Replicate flow = corr - base; grid = base + flow (extra roundings).
        float base_x = (float)xp, base_y = py;
        float fx = corr_x - base_x;
        float fy = corr_y - base_y;
        float gxv = base_x + fx;
        float gyv = base_y + fy;

        float gx = ((2.0f * gxv) / (float)(WP_ - 1)) - 1.0f;
        float gy = ((2.0f * gyv) / (float)(H_  - 1)) - 1.0f;
        float cm = bg ? 2.0f : (has_corr ? 0.0f : 1.0f);

        vfloat2 ov = { gx, gy };
        ogrow[xp] = ov;            // 512B/instr, full lines, cached
        cmrow[xp] = cm;            // 256B/instr, full lines, cached
    }
}

extern "C" void kernel_launch(void* const* d_in, const int* in_sizes, int n_in,
                              void* d_out, int out_size, void* d_ws, size_t ws_size,
                              hipStream_t stream)
{
    const float* verts_1 = (const float*)d_in[0];
    const int*   vis_1   = (const int*)d_in[1];
    const float* verts_2 = (const float*)d_in[2];
    const int*   vis_2   = (const int*)d_in[3];
    const int*   face    = (const int*)d_in[4];
    const float* vis_sym = (const float*)d_in[5];
    const int*   symtab  = (const int*)d_in[6];

    float* out_grid  = (float*)d_out;                              // B*H*WP*2
    float* corr_mask = (float*)d_out + (size_t)B_ * H_ * WP_ * 2;  // B*H*WP

    // Workspace: [vf2: B*F bytes][align 64][recs: B*F*32 bytes]
    unsigned char* vf2 = (unsigned char*)d_ws;
    size_t rec_off = ((size_t)B_ * F_ + 63) & ~(size_t)63;
    float4* recs = (float4*)((unsigned char*)d_ws + rec_off);

    (void)hipMemsetAsync(vf2, 0, (size_t)B_ * F_, stream);

    {
        const int total4 = B_ * H_ * W_ / 4;          // 1572864
        const int block  = 256;
        const int grid   = total4 / block;            // 6144, %8 == 0
        vf2_scatter_kernel<<<grid, block, 0, stream>>>(
            (const vint4*)vis_2, vf2);
    }
    {
        const int total = B_ * F_;                    // 440832
        const int block = 256;
        face_precompute_kernel<<<(total + block - 1) / block, block, 0, stream>>>(
            verts_1, verts_2, face, symtab, vf2, recs);
    }
    {
        const int rows  = B_ * H_;                    // 16384 rows, 1 wave/row
        const int block = 256;                        // 4 waves/block
        const int grid  = rows / 4;                   // 4096, %8 == 0
        flow_main_kernel<<<grid, block, 0, stream>>>(
            vis_1, vis_sym, recs, out_grid, corr_mask);
    }
}

// Round 11
// 93.628 us; speedup vs baseline: 1.4069x; 1.0188x over previous
//
#include <hip/hip_runtime.h>

// f32 parts that must be bit-exact vs numpy (denom chain, clamps) forbid FMA
// contraction. The affine-coefficient algebra is done in f64 and rounded once.
#pragma clang fp contract(off)

#define B_ 32
#define H_ 512
#define W_ 384
#define V_ 6890
#define F_ 13776
#define PAD_ 64          // (H - W) / 2
#define WP_ 512          // W + 2*PAD

typedef int   vint4   __attribute__((ext_vector_type(4)));
typedef float vfloat2 __attribute__((ext_vector_type(2)));
typedef float vfloat4 __attribute__((ext_vector_type(4)));

// RULES learned this session:
// r7: partial-line nontemporal amplifies HBM traffic ~1.5x.
// r9: ANY nt in the main kernel costs ~30us OUTSIDE its own dispatch window
//     => NO nontemporal anywhere; all streaming accesses cached.
// r10: record compression below f32 mantissa is numerically impossible
//     (measured absmax 32768 => cancellation terms ~1.4e14; threshold allows
//     <= ~7x f32 error). Gather stays 32B = 2 x dwordx4.
// r11 experiment: sc0 (L1-bypass, device-coherent) on the random gathers to
//     escape the ~32-entry L1 MSHR limit (model: 0.107 miss/cy = 75us match).

// Per-(b,f) record: 32 bytes (2 records per 64B line).
// r0: [A'x, Bx, Cx, A'y]   corr_x = A'x + px*Bx + py*Cx
// r1: [By, Cy, flags, 0]   corr_y = A'y + px*By + py*Cy
// flags bit0 = vis2f, bit1 = sym_ok.

// ---------------------------------------------------------------------------
// Kernel 1: vf2[b][f] = any view-2 pixel sees face f. Plain cached int4
// reads, idempotent byte stores. XCD-chunk swizzled.
// ---------------------------------------------------------------------------
__global__ __launch_bounds__(256) void vf2_scatter_kernel(
    const vint4* __restrict__ vis_2_v4, unsigned char* __restrict__ vf2)
{
    unsigned bid = blockIdx.x;
    unsigned cpx = gridDim.x >> 3;                 // gridDim divisible by 8
    unsigned swz = (bid & 7u) * cpx + (bid >> 3);
    int idx = (int)(swz * blockDim.x + threadIdx.x);
    const int total4 = B_ * H_ * W_ / 4;
    if (idx >= total4) return;
    vint4 v = vis_2_v4[idx];
    int b = idx / (H_ * W_ / 4);                   // groups never cross b
    unsigned char* t = vf2 + (size_t)b * F_;
    if (v.x >= 0) t[v.x] = 1;
    if (v.y >= 0) t[v.y] = 1;
    if (v.z >= 0) t[v.z] = 1;
    if (v.w >= 0) t[v.w] = 1;
}

// ---------------------------------------------------------------------------
// Kernel 2: build 32B affine records. denom/flags bit-exact in f32 (ref op
// order); coefficient algebra in f64, rounded once to f32.
// ---------------------------------------------------------------------------
__global__ __launch_bounds__(256) void face_precompute_kernel(
    const float* __restrict__ verts_1,
    const float* __restrict__ verts_2,
    const int*   __restrict__ face,
    const int*   __restrict__ symtab,
    const unsigned char* __restrict__ vf2,
    float4* __restrict__ recs)            // B*F*2 float4s
{
#pragma clang fp contract(off)
    int idx = blockIdx.x * blockDim.x + threadIdx.x;
    const int total = B_ * F_;
    if (idx >= total) return;
    int f = idx % F_;
    int b = idx / F_;

    int i0 = face[f * 3 + 0];
    int i1 = face[f * 3 + 1];
    int i2 = face[f * 3 + 2];

    const float* v1b = verts_1 + (size_t)b * (V_ * 3);
    float ax = v1b[i0 * 3 + 0], ay = v1b[i0 * 3 + 1];
    float bx = v1b[i1 * 3 + 0], by = v1b[i1 * 3 + 1];
    float cx = v1b[i2 * 3 + 0], cy = v1b[i2 * 3 + 1];

    // f32, exact reference op order (these feed the denom clamp decision).
    float e0x = bx - ax, e0y = by - ay;
    float e1x = cx - ax, e1y = cy - ay;
    float d00 = (e0x * e0x) + (e0y * e0y);
    float d01 = (e0x * e1x) + (e0y * e1y);
    float d11 = (e1x * e1x) + (e1y * e1y);
    float denom = (d00 * d11) - (d01 * d01);
    if (fabsf(denom) < 1e-12f) denom = 1.0f;

    bool vis2f = vf2[idx] != 0;
    int s0 = symtab[i0], s1 = symtab[i1], s2 = symtab[i2];
    bool sym_ok = (s0 >= 0) && (s1 >= 0) && (s2 >= 0);

    int t0 = (!vis2f && sym_ok) ? s0 : i0;
    int t1 = (!vis2f && sym_ok) ? s1 : i1;
    int t2 = (!vis2f && sym_ok) ? s2 : i2;

    const float* v2b = verts_2 + (size_t)b * (V_ * 3);
    float q0x = v2b[t0 * 3 + 0], q0y = v2b[t0 * 3 + 1];
    float q1x = v2b[t1 * 3 + 0], q1y = v2b[t1 * 3 + 1];
    float q2x = v2b[t2 * 3 + 0], q2y = v2b[t2 * 3 + 1];

    // f64 affine algebra: corr_x = A'x + px*Bx + py*Cx  (e2 = p - a folded)
    double dd00 = (double)d00, dd01 = (double)d01, dd11 = (double)d11;
    double dden = (double)denom;
    double De0x = (double)e0x, De0y = (double)e0y;
    double De1x = (double)e1x, De1y = (double)e1y;

    double Ux = (dd11 * De0x - dd01 * De1x) / dden;
    double Uy = (dd11 * De0y - dd01 * De1y) / dden;
    double Vx = (dd00 * De1x - dd01 * De0x) / dden;
    double Vy = (dd00 * De1y - dd01 * De0y) / dden;

    double dq1x = (double)q1x - (double)q0x;
    double dq2x = (double)q2x - (double)q0x;
    double dq1y = (double)q1y - (double)q0y;
    double dq2y = (double)q2y - (double)q0y;

    double Bx = Ux * dq1x + Vx * dq2x;
    double Cx = Uy * dq1x + Vy * dq2x;
    double By = Ux * dq1y + Vx * dq2y;
    double Cy = Uy * dq1y + Vy * dq2y;

    double Apx = (double)q0x - (double)ax * Bx - (double)ay * Cx;
    double Apy = (double)q0y - (double)ax * By - (double)ay * Cy;

    unsigned flags = (vis2f ? 1u : 0u) | (sym_ok ? 2u : 0u);

    float4* r = recs + (size_t)idx * 2;
    r[0] = make_float4((float)Apx, (float)Bx, (float)Cx, (float)Apy);
    r[1] = make_float4((float)By, (float)Cy, __uint_as_float(flags), 0.0f);
}

// ---------------------------------------------------------------------------
// Kernel 3: main. One wave = one 512-px padded row; lane l owns pixel
// xp = k*64+l of group k (k=0..7); groups 0/7 are pad. Streaming accesses
// lane-contiguous cached (r9). Record gathers use sc0 (L1-bypass) inline-asm
// loads: random 64B-line misses have ~no L1 reuse, and bypassing L1 lifts
// the ~32-entry MSHR ceiling (12 in-flight/wave x ~20 waves/CU instead).
// ---------------------------------------------------------------------------
__global__ __launch_bounds__(256) void flow_main_kernel(
    const int*   __restrict__ vis_1,
    const float* __restrict__ vis_sym_mask_1,
    const float4* __restrict__ recs,
    float* __restrict__ out_grid,    // B*H*WP*2 floats
    float* __restrict__ corr_mask)   // B*H*WP floats
{
#pragma clang fp contract(off)
    unsigned bid = blockIdx.x;
    unsigned cpx = gridDim.x >> 3;                 // 4096/8 = 512
    unsigned swz = (bid & 7u) * cpx + (bid >> 3);
    int gtid = (int)(swz * blockDim.x + threadIdx.x);
    int row  = gtid >> 6;                          // in [0, B*H)
    int lane = (int)(threadIdx.x & 63u);
    int y = row & (H_ - 1);
    int b = row >> 9;                              // row / H_

    const int*   visrow = vis_1          + (size_t)row * W_;
    const float* mskrow = vis_sym_mask_1 + (size_t)row * W_;
    vfloat2*     ogrow  = (vfloat2*)out_grid + (size_t)row * WP_;
    float*       cmrow  = corr_mask      + (size_t)row * WP_;

    // Pad groups k=0 and k=7: full-line constant stores.
    {
        vfloat2 pv = { -1.0f, -1.0f };
        ogrow[lane]       = pv;
        ogrow[448 + lane] = pv;
        cmrow[lane]       = 2.0f;
        cmrow[448 + lane] = 2.0f;
    }

    // Interior groups j=0..5: x = j*64+lane, xp = x+64.
    int   vis[6];
    float msk[6];
    #pragma unroll
    for (int j = 0; j < 6; ++j) {
        vis[j] = visrow[j * 64 + lane];
        msk[j] = mskrow[j * 64 + lane];
    }

    // Issue all 12 record loads with sc0 (L1 bypass), then one drain.
    vfloat4 R0[6], R1[6];
    bool    bgs[6];
    #pragma unroll
    for (int j = 0; j < 6; ++j) {
        bgs[j] = vis[j] < 0;
        int fc = bgs[j] ? 0 : vis[j];
        const char* addr = (const char*)recs + ((size_t)b * F_ + fc) * 32;
        asm volatile("global_load_dwordx4 %0, %2, off sc0\n\t"
                     "global_load_dwordx4 %1, %2, off offset:16 sc0"
                     : "=&v"(R0[j]), "=&v"(R1[j])
                     : "v"(addr));
    }
    asm volatile("s_waitcnt vmcnt(0)" ::: "memory");
    __builtin_amdgcn_sched_barrier(0);

    #pragma unroll
    for (int j = 0; j < 6; ++j) {
        float Apx = R0[j].x, Bx = R0[j].y, Cx = R0[j].z, Apy = R0[j].w;
        float By  = R1[j].x, Cy = R1[j].y;
        unsigned flags = __float_as_uint(R1[j].z);
        bool vis2f  = (flags & 1u) != 0;
        bool sym_ok = (flags & 2u) != 0;

        int   x  = j * 64 + lane;
        int   xp = x + PAD_;
        float px = (float)x, py = (float)y;

        float corr_x = ((px * Bx) + (py * Cx)) + Apx;
        float corr_y = ((px * By) + (py * Cy)) + Apy;

        bool bg = bgs[j];
        bool use_sym  = (!vis2f) && sym_ok && (msk[j] > 0.0f) && (!bg);
        bool has_corr = (!bg) && (vis2f || use_sym);
        if (!has_corr) { corr_x = 0.0f; corr_y = 0.0f; }

        corr_x = corr_x + (float)PAD_;

        // Replicate flow = corr - base; grid = base + flow (extra roundings).
        float base_x = (float)xp, base_y = py;
        float fx = corr_x - base_x;
        float fy = corr_y - base_y;
        float gxv = base_x + fx;
        float gyv = base_y + fy;

        float gx = ((2.0f * gxv) / (float)(WP_ - 1)) - 1.0f;
        float gy = ((2.0f * gyv) / (float)(H_  - 1)) - 1.0f;
        float cm = bg ? 2.0f : (has_corr ? 0.0f : 1.0f);

        vfloat2 ov = { gx, gy };
        ogrow[xp] = ov;            // 512B/instr, full lines, cached
        cmrow[xp] = cm;            // 256B/instr, full lines, cached
    }
}

extern "C" void kernel_launch(void* const* d_in, const int* in_sizes, int n_in,
                              void* d_out, int out_size, void* d_ws, size_t ws_size,
                              hipStream_t stream)
{
    const float* verts_1 = (const float*)d_in[0];
    const int*   vis_1   = (const int*)d_in[1];
    const float* verts_2 = (const float*)d_in[2];
    const int*   vis_2   = (const int*)d_in[3];
    const int*   face    = (const int*)d_in[4];
    const float* vis_sym = (const float*)d_in[5];
    const int*   symtab  = (const int*)d_in[6];

    float* out_grid  = (float*)d_out;                              // B*H*WP*2
    float* corr_mask = (float*)d_out + (size_t)B_ * H_ * WP_ * 2;  // B*H*WP

    // Workspace: [vf2: B*F bytes][align 64][recs: B*F*32 bytes]
    unsigned char* vf2 = (unsigned char*)d_ws;
    size_t rec_off = ((size_t)B_ * F_ + 63) & ~(size_t)63;
    float4* recs = (float4*)((unsigned char*)d_ws + rec_off);

    (void)hipMemsetAsync(vf2, 0, (size_t)B_ * F_, stream);

    {
        const int total4 = B_ * H_ * W_ / 4;          // 1572864
        const int block  = 256;
        const int grid   = total4 / block;            // 6144, %8 == 0
        vf2_scatter_kernel<<<grid, block, 0, stream>>>(
            (const vint4*)vis_2, vf2);
    }
    {
        const int total = B_ * F_;                    // 440832
        const int block = 256;
        face_precompute_kernel<<<(total + block - 1) / block, block, 0, stream>>>(
            verts_1, verts_2, face, symtab, vf2, recs);
    }
    {
        const int rows  = B_ * H_;                    // 16384 rows, 1 wave/row
        const int block = 256;                        // 4 waves/block
        const int grid  = rows / 4;                   // 4096, %8 == 0
        flow_main_kernel<<<grid, block, 0, stream>>>(
            vis_1, vis_sym, recs, out_grid, corr_mask);
    }
}